// Round 24
// baseline (207.342 us; speedup 1.0000x reference)
//
#include <hip/hip_runtime.h>
#include <stdint.h>

#define B_ 8
#define C_ 256
#define H_ 96
#define W_ 160
#define ND 9
#define NDISP 81
#define NCHUNK 128             // channel-pairs
#define TX 8
#define NXG 5                  // x-groups per quarter (40 = 5*8)
#define NTHR 64                // ONE wave per block: no barriers at all
#define NCOMP 45               // 9 dy * 5 xg
// Per-buffer f16-pair layout (bytes): in1: 40 words @0 (160 B);
// in2 row r(=dy): 48 words (x in [40q-4, 40q+44)) @ 160 + r*192.
#define IN2_OFF 160
#define ROW_B 192              // 12*16
#define BUF_B 1888             // 160 + 9*192 = 1888 = 118*16
#define NSEG 118               // uint4 segments/chunk
#define HW (H_ * W_)
#define CHSTEP (2 * HW)        // channel-pair step

typedef __attribute__((ext_vector_type(2))) _Float16 half2v;

__device__ __forceinline__ unsigned pk(float lo, float hi) {
    return __builtin_bit_cast(unsigned, __builtin_amdgcn_cvt_pkrtz(lo, hi));
}
__device__ __forceinline__ float dot2acc(unsigned a, unsigned w, float acc) {
#if __has_builtin(__builtin_amdgcn_fdot2)
    return __builtin_amdgcn_fdot2(__builtin_bit_cast(half2v, a),
                                  __builtin_bit_cast(half2v, w), acc, false);
#else
    float r;
    asm("v_dot2_f32_f16 %0, %1, %2, %3"
        : "=v"(r) : "v"(a), "v"(w), "v"(acc));
    return r;
#endif
}

// uint4 segment s -> fp32 source (even-channel base) + LDS byte offset.
// Clamped cells hold finite garbage, masked at dot2/store time.
__device__ __forceinline__ const float* seg_src(int s, int b, int y, int q,
        const float* in1, const float* in2, int* woff)
{
    if (s < 10) {                          // in1: x = 40q + 4s (all real)
        *woff = s * 16;
        return in1 + ((size_t)(b * C_) * H_ + y) * W_ + 40 * q + 4 * s;
    }
    const int t = s - 10;
    const int r = t / 12, k = t - r * 12;  // dy row, word-seg
    *woff = IN2_OFF + r * ROW_B + k * 16;
    int row = y + r - 4;
    row = row < 0 ? 0 : (row >= H_ ? H_ - 1 : row);      // clamp; masked later
    int x = 40 * q - 4 + 4 * k;
    x = x < 0 ? 0 : (x > W_ - 4 ? W_ - 4 : x);           // clamp; masked later
    return in2 + ((size_t)(b * C_) * H_ + row) * W_ + x; // 16B-aligned
}

__global__ __launch_bounds__(NTHR) void corr_q1w_kernel(
    const float* __restrict__ in1,
    const float* __restrict__ in2,
    float* __restrict__ out)
{
    __shared__ __align__(16) unsigned lds[2 * BUF_B / 4];   // 3776 B

    const int tid  = threadIdx.x;
    const int b    = blockIdx.x & 7;      // XCD swizzle: batch pinned to XCD
    const int rest = blockIdx.x >> 3;     // 0..383
    const int y    = rest >> 2;
    const int q    = rest & 3;            // x quarter

    // ---- staging slots: seg tid (always valid) and tid+64 (tid < 54)
    int w0off = 0, w1off = 0;
    const float* p0 = seg_src(tid, b, y, q, in1, in2, &w0off);
    const bool v1 = (tid + 64) < NSEG;
    const float* p1 = in1;                // safe dummy
    if (v1) p1 = seg_src(tid + 64, b, y, q, in1, in2, &w1off);

    // ---- compute coords (lanes 0..44): dy-major; others broadcast lane 0
    const bool isComp = (tid < NCOMP);
    const int  dy = isComp ? (tid / NXG) : 0;
    const int  xg = isComp ? (tid % NXG) : 0;
    const int  x0 = 40 * q + TX * xg;
    const bool rowOk = (y + dy - 4 >= 0) && (y + dy - 4 < H_);
    const bool mzW0 = (q == 0) && (xg == 0);        // words x [-4,0)
    const bool mzW3 = (q == 3) && (xg == NXG - 1);  // words x [160,164)

    const int aof = 32 * xg;                         // in1 words [8xg, 8xg+8)
    const int wof = IN2_OFF + dy * ROW_B + 32 * xg;  // in2 words [8xg-4,8xg+12)

    float acc[ND][TX];
    #pragma unroll
    for (int dx = 0; dx < ND; ++dx)
        #pragma unroll
        for (int j = 0; j < TX; ++j) acc[dx][j] = 0.f;

    // staging regs, single set (CVTW consumes, LOADS refills — R16 pattern)
    float4 Sp0, Sp1, Sq0, Sq1;

    #define LOADS do {                                                        \
        Sp0 = *(const float4*)(p0);  Sp1 = *(const float4*)(p0 + HW);         \
        Sq0 = *(const float4*)(p1);  Sq1 = *(const float4*)(p1 + HW);         \
        p0 += CHSTEP; p1 += CHSTEP;                                           \
    } while (0);

    #define CVTW(BUFI) do {                                                   \
        char* base = (char*)lds + (BUFI) * BUF_B;                             \
        *(uint4*)(base + w0off) = make_uint4(                                 \
            pk(Sp0.x, Sp1.x), pk(Sp0.y, Sp1.y),                               \
            pk(Sp0.z, Sp1.z), pk(Sp0.w, Sp1.w));                              \
        if (v1) *(uint4*)(base + w1off) = make_uint4(                         \
            pk(Sq0.x, Sq1.x), pk(Sq0.y, Sq1.y),                               \
            pk(Sq0.z, Sq1.z), pk(Sq0.w, Sq1.w));                              \
    } while (0);

    #define COMPUTE(BUFI) {                                                   \
        const char* bb = (const char*)lds + (BUFI) * BUF_B;                   \
        uint4 A0 = *(const uint4*)(bb + aof);                                 \
        uint4 A1 = *(const uint4*)(bb + aof + 16);                            \
        uint4 W0 = *(const uint4*)(bb + wof);                                 \
        uint4 W1 = *(const uint4*)(bb + wof + 16);                            \
        uint4 W2 = *(const uint4*)(bb + wof + 32);                            \
        uint4 W3 = *(const uint4*)(bb + wof + 48);                            \
        if (mzW0) W0 = make_uint4(0u, 0u, 0u, 0u);                            \
        if (mzW3) W3 = make_uint4(0u, 0u, 0u, 0u);                            \
        unsigned a[8]  = {A0.x, A0.y, A0.z, A0.w, A1.x, A1.y, A1.z, A1.w};    \
        unsigned w[16] = {W0.x, W0.y, W0.z, W0.w, W1.x, W1.y, W1.z, W1.w,     \
                          W2.x, W2.y, W2.z, W2.w, W3.x, W3.y, W3.z, W3.w};    \
        _Pragma("unroll")                                                     \
        for (int dx = 0; dx < ND; ++dx) {                                     \
            _Pragma("unroll")                                                 \
            for (int j = 0; j < TX; ++j)                                      \
                acc[dx][j] = dot2acc(a[j], w[dx + j], acc[dx][j]);            \
        }                                                                     \
    }

    // body kc (wave-local, NO barrier, NO waitcnt asm — compiler tracks
    // deps; LDS ops within a wave are in-order, R16-verified pattern):
    //   COMPUTE kc from buf kc&1 (written body kc-1);
    //   CVTW kc+1 into buf (kc+1)&1 (regs from body kc-1's LOADS — one
    //   full body of vmcnt slack);  LOADS kc+2.
    #define BODY(BUFI, DOW, DOL)                                              \
        COMPUTE(BUFI)                                                         \
        if (DOW) { CVTW((BUFI) ^ 1) }                                         \
        if (DOL) { LOADS }

    // ---- prologue: c0 -> buf0; c1 raw in regs
    LOADS              // c0
    CVTW(0)
    LOADS              // c1

    // ---- main loop: kc = 0..125
    #pragma unroll 1
    for (int g = 0; g < 63; ++g) {
        BODY(0, true, true)
        BODY(1, true, true)
    }
    // ---- tail: kc = 126 (writes c127), kc = 127
    BODY(0, true, false)
    BODY(1, false, false)

    #undef BODY
    #undef COMPUTE
    #undef CVTW
    #undef LOADS

    // ---- epilogue: OOB-dy rows output zeros via masked scale
    if (isComp) {
        const float m = rowOk ? (1.0f / (float)C_) : 0.f;
        float* outp = out + ((size_t)(b * NDISP + dy * ND) * H_ + y) * W_ + x0;
        #pragma unroll
        for (int dx = 0; dx < ND; ++dx) {
            float4 o0 = make_float4(acc[dx][0] * m, acc[dx][1] * m,
                                    acc[dx][2] * m, acc[dx][3] * m);
            float4 o1 = make_float4(acc[dx][4] * m, acc[dx][5] * m,
                                    acc[dx][6] * m, acc[dx][7] * m);
            *(float4*)(outp + dx * HW)     = o0;
            *(float4*)(outp + dx * HW + 4) = o1;
        }
    }
}

extern "C" void kernel_launch(void* const* d_in, const int* in_sizes, int n_in,
                              void* d_out, int out_size, void* d_ws, size_t ws_size,
                              hipStream_t stream) {
    const float* in1 = (const float*)d_in[0];
    const float* in2 = (const float*)d_in[1];
    float* out = (float*)d_out;

    const int grid = B_ * H_ * 4;   // 3072 single-wave blocks = 12 waves/CU
    corr_q1w_kernel<<<grid, NTHR, 0, stream>>>(in1, in2, out);
}

// Round 25
// 116.136 us; speedup vs baseline: 1.7853x; 1.7853x over previous
//
#include <hip/hip_runtime.h>
#include <stdint.h>

#define B_ 8
#define C_ 256
#define H_ 96
#define W_ 160
#define ND 9
#define NDISP 81
#define NCHUNK 128             // channel-pairs
#define TX 4
#define NXG 20                 // x-groups per half (80 = 20*4)
#define NTHR 256               // 4 waves
#define NCOMP 180              // 9 dy * 20 xg
// Per-buffer f16-pair layout (bytes): in1: 80 words @0 (320 B);
// in2 row r(=dy): 88 words (x in [80h-4, 80h+84)) @ 320 + r*352.
#define IN2_OFF 320
#define ROW_B 352              // 22*16
#define BUF_B 3584             // 3488 padded
#define NBUF 4                 // write-ahead-2
#define NSEG 218               // uint4 segments/chunk: 20 in1 + 9*22 in2
#define HW (H_ * W_)
#define CHSTEP (2 * HW)        // channel-pair step

typedef __attribute__((ext_vector_type(2))) _Float16 half2v;

__device__ __forceinline__ unsigned pk(float lo, float hi) {
    return __builtin_bit_cast(unsigned, __builtin_amdgcn_cvt_pkrtz(lo, hi));
}
__device__ __forceinline__ float dot2acc(unsigned a, unsigned w, float acc) {
#if __has_builtin(__builtin_amdgcn_fdot2)
    return __builtin_amdgcn_fdot2(__builtin_bit_cast(half2v, a),
                                  __builtin_bit_cast(half2v, w), acc, false);
#else
    half2v av = __builtin_bit_cast(half2v, a);
    half2v wv = __builtin_bit_cast(half2v, w);
    return acc + (float)av.x * (float)wv.x + (float)av.y * (float)wv.y;
#endif
}

// Raw barrier, lgkm drain only (ds_write visibility). NO vmcnt drain:
// global-load slack must survive the barrier (R23-verified safe).
__device__ __forceinline__ void block_barrier_lgkm() {
    asm volatile("s_waitcnt lgkmcnt(0)" ::: "memory");
    __builtin_amdgcn_s_barrier();
    asm volatile("" ::: "memory");
    __builtin_amdgcn_sched_barrier(0);
}

// uint4 segment s -> fp32 source (even-channel base) + LDS byte offset.
__device__ __forceinline__ const float* seg_src(int s, int b, int y, int h,
        const float* in1, const float* in2, int* woff)
{
    if (s < 20) {                          // in1: x = 80h + 4s (all real)
        *woff = s * 16;
        return in1 + ((size_t)(b * C_) * H_ + y) * W_ + 80 * h + 4 * s;
    }
    const int t = s - 20;
    const int r = t / 22, k = t - r * 22;  // dy row, word-seg
    *woff = IN2_OFF + r * ROW_B + k * 16;
    int row = y + r - 4;
    row = row < 0 ? 0 : (row >= H_ ? H_ - 1 : row);      // clamp; masked later
    int x = 80 * h - 4 + 4 * k;
    x = x < 0 ? 0 : (x > W_ - 4 ? W_ - 4 : x);           // clamp; masked later
    return in2 + ((size_t)(b * C_) * H_ + row) * W_ + x; // 16B-aligned
}

__global__ __launch_bounds__(NTHR) void corr_s3_kernel(
    const float* __restrict__ in1,
    const float* __restrict__ in2,
    float* __restrict__ out)
{
    __shared__ __align__(16) unsigned lds[NBUF * BUF_B / 4];   // 14336 B

    const int tid = threadIdx.x;
    const int b   = blockIdx.x & 7;       // XCD swizzle
    const int idx = blockIdx.x >> 3;      // 0..191
    const int y   = idx >> 1;
    const int h   = idx & 1;              // x half

    // ---- staging slot (1 per thread; invalid for tid >= 218)
    int w0off = 0;
    const bool v0 = tid < NSEG;
    const float* p0 = in1;                // safe dummy (stays in-bounds)
    if (v0) p0 = seg_src(tid, b, y, h, in1, in2, &w0off);

    // ---- compute coords (lanes 0..179): dy-major
    const bool isComp = (tid < NCOMP);
    const int  dy = isComp ? (tid / NXG) : 0;
    const int  xg = isComp ? (tid % NXG) : 0;
    const int  x0 = 80 * h + TX * xg;
    const bool rowOk = (y + dy - 4 >= 0) && (y + dy - 4 < H_);
    const bool mzW0 = (h == 0) && (xg == 0);        // words x [-4,0)
    const bool mzW2 = (h == 1) && (xg == NXG - 1);  // words x [160,164)

    const int aof = 16 * xg;                         // in1 words [4xg, 4xg+4)
    const int wof = IN2_OFF + dy * ROW_B + 16 * xg;  // in2 words [4xg-4,4xg+8)

    float acc[ND][TX];
    #pragma unroll
    for (int dx = 0; dx < ND; ++dx)
        #pragma unroll
        for (int j = 0; j < TX; ++j) acc[dx][j] = 0.f;

    // THREE staging sets -> 2-body slack from LOADS to CVTW (> HBM ~900 cy).
    // (letter-first suffixes — R17 pp-number lesson)
    float4 SAp0, SAp1;
    float4 SBp0, SBp1;
    float4 SCp0, SCp1;

    #define LOADS(S) do {                                                     \
        S##p0 = *(const float4*)(p0);  S##p1 = *(const float4*)(p0 + HW);     \
        p0 += CHSTEP;                                                         \
    } while (0);

    #define CVTW(BUFI, S) do {                                                \
        if (v0) {                                                             \
            char* base = (char*)lds + (BUFI) * BUF_B;                         \
            *(uint4*)(base + w0off) = make_uint4(                             \
                pk(S##p0.x, S##p1.x), pk(S##p0.y, S##p1.y),                   \
                pk(S##p0.z, S##p1.z), pk(S##p0.w, S##p1.w));                  \
        }                                                                     \
    } while (0);

    #define COMPUTE(BUFI)                                                     \
    if (isComp) {                                                             \
        const char* bb = (const char*)lds + (BUFI) * BUF_B;                   \
        uint4 A0 = *(const uint4*)(bb + aof);                                 \
        uint4 W0 = *(const uint4*)(bb + wof);                                 \
        uint4 W1 = *(const uint4*)(bb + wof + 16);                            \
        uint4 W2 = *(const uint4*)(bb + wof + 32);                            \
        if (mzW0) W0 = make_uint4(0u, 0u, 0u, 0u);                            \
        if (mzW2) W2 = make_uint4(0u, 0u, 0u, 0u);                            \
        unsigned a[4]  = {A0.x, A0.y, A0.z, A0.w};                            \
        unsigned w[12] = {W0.x, W0.y, W0.z, W0.w, W1.x, W1.y, W1.z, W1.w,     \
                          W2.x, W2.y, W2.z, W2.w};                            \
        _Pragma("unroll")                                                     \
        for (int dx = 0; dx < ND; ++dx) {                                     \
            _Pragma("unroll")                                                 \
            for (int j = 0; j < TX; ++j)                                      \
                acc[dx][j] = dot2acc(a[j], w[dx + j], acc[dx][j]);            \
        }                                                                     \
    }

    // body kc: COMPUTE buf kc&3 (written body kc-2, 2 barriers ago);
    // CVTW chunk kc+2 into buf (kc+2)&3 from set (kc+2)%3 (loaded body kc-2
    // -> ~2 bodies of vmcnt slack, > HBM latency); LOADS chunk kc+4 into
    // set (kc+1)%3 (its chunk kc+1 was consumed in body kc-1); raw barrier.
    #define BODY(BUFC, BUFW, SW, SL, DOW, DOL)                                \
        COMPUTE(BUFC)                                                         \
        if (DOW) { CVTW(BUFW, SW) }                                           \
        if (DOL) { LOADS(SL) }                                                \
        block_barrier_lgkm();

    // ---- prologue: c0->buf0, c1->buf1; c2 in SC, c3 in SA
    LOADS(SA)          // c0
    CVTW(0, SA)
    LOADS(SB)          // c1
    CVTW(1, SB)
    LOADS(SC)          // c2
    LOADS(SA)          // c3
    block_barrier_lgkm();

    // ---- main loop: kc = 0..119 (period 12 = lcm(3 sets, 4 bufs))
    #pragma unroll 1
    for (int g = 0; g < 10; ++g) {
        BODY(0, 2, SC, SB, true, true)   // kc%12=0:  W c+2(SC), L c+4->SB
        BODY(1, 3, SA, SC, true, true)   // 1
        BODY(2, 0, SB, SA, true, true)   // 2
        BODY(3, 1, SC, SB, true, true)   // 3
        BODY(0, 2, SA, SC, true, true)   // 4
        BODY(1, 3, SB, SA, true, true)   // 5
        BODY(2, 0, SC, SB, true, true)   // 6
        BODY(3, 1, SA, SC, true, true)   // 7
        BODY(0, 2, SB, SA, true, true)   // 8
        BODY(1, 3, SC, SB, true, true)   // 9
        BODY(2, 0, SA, SC, true, true)   // 10
        BODY(3, 1, SB, SA, true, true)   // 11
    }
    // ---- tail: kc = 120..127
    BODY(0, 2, SC, SB, true, true)    // c122 written, c124 -> SB
    BODY(1, 3, SA, SC, true, true)    // c123, c125 -> SC
    BODY(2, 0, SB, SA, true, true)    // c124, c126 -> SA
    BODY(3, 1, SC, SB, true, true)    // c125, c127 -> SB
    BODY(0, 2, SA, SA, true, false)   // c126 written
    BODY(1, 3, SB, SA, true, false)   // c127 written
    BODY(2, 0, SA, SA, false, false)
    COMPUTE(3)                        // kc = 127

    #undef BODY
    #undef COMPUTE
    #undef CVTW
    #undef LOADS

    // ---- epilogue: OOB-dy rows output zeros via masked scale
    if (isComp) {
        const float m = rowOk ? (1.0f / (float)C_) : 0.f;
        float* outp = out + ((size_t)(b * NDISP + dy * ND) * H_ + y) * W_ + x0;
        #pragma unroll
        for (int dx = 0; dx < ND; ++dx) {
            float4 o = make_float4(acc[dx][0] * m, acc[dx][1] * m,
                                   acc[dx][2] * m, acc[dx][3] * m);
            *(float4*)(outp + dx * HW) = o;
        }
    }
}

extern "C" void kernel_launch(void* const* d_in, const int* in_sizes, int n_in,
                              void* d_out, int out_size, void* d_ws, size_t ws_size,
                              hipStream_t stream) {
    const float* in1 = (const float*)d_in[0];
    const float* in2 = (const float*)d_in[1];
    float* out = (float*)d_out;

    const int grid = B_ * H_ * 2;   // 1536 blocks (b, y, half) = 6 per CU
    corr_s3_kernel<<<grid, NTHR, 0, stream>>>(in1, in2, out);
}

// Round 26
// 112.351 us; speedup vs baseline: 1.8455x; 1.0337x over previous
//
#include <hip/hip_runtime.h>
#include <stdint.h>

#define B_ 8
#define C_ 256
#define H_ 96
#define W_ 160
#define ND 9
#define NDISP 81
#define NCHUNK 128             // channel-pairs
#define TX 4
#define NXG 20                 // x-groups per half (80 = 20*4)
#define NTHR 256               // 4 waves
#define NCOMP 180              // 9 dy * 20 xg
// Per-buffer f16-pair layout (bytes): in1: 80 words @0 (320 B);
// in2 row r(=dy): 88 words (x in [80h-4, 80h+84)) @ 320 + r*352.
#define IN2_OFF 320
#define ROW_B 352              // 22*16
#define BUF_B 3584             // 320 + 9*352 = 3488, padded to 16-mult
#define NBUF 4                 // write-ahead-2 -> ONE barrier per chunk
#define NSEG 218               // uint4 segments/chunk: 20 in1 + 9*22 in2
#define HW (H_ * W_)
#define CHSTEP (2 * HW)        // channel-pair step

typedef __attribute__((ext_vector_type(2))) _Float16 half2v;

__device__ __forceinline__ unsigned pk(float lo, float hi) {
    return __builtin_bit_cast(unsigned, __builtin_amdgcn_cvt_pkrtz(lo, hi));
}
__device__ __forceinline__ float dot2acc(unsigned a, unsigned w, float acc) {
#if __has_builtin(__builtin_amdgcn_fdot2)
    return __builtin_amdgcn_fdot2(__builtin_bit_cast(half2v, a),
                                  __builtin_bit_cast(half2v, w), acc, false);
#else
    half2v av = __builtin_bit_cast(half2v, a);
    half2v wv = __builtin_bit_cast(half2v, w);
    return acc + (float)av.x * (float)wv.x + (float)av.y * (float)wv.y;
#endif
}

// uint4 segment s -> fp32 source (even-channel base) + LDS byte offset.
__device__ __forceinline__ const float* seg_src(int s, int b, int y, int h,
        const float* in1, const float* in2, int* woff)
{
    if (s < 20) {                          // in1: x = 80h + 4s (all real)
        *woff = s * 16;
        return in1 + ((size_t)(b * C_) * H_ + y) * W_ + 80 * h + 4 * s;
    }
    const int t = s - 20;
    const int r = t / 22, k = t - r * 22;  // dy row, word-seg
    *woff = IN2_OFF + r * ROW_B + k * 16;
    int row = y + r - 4;
    row = row < 0 ? 0 : (row >= H_ ? H_ - 1 : row);      // clamp; masked later
    int x = 80 * h - 4 + 4 * k;
    x = x < 0 ? 0 : (x > W_ - 4 ? W_ - 4 : x);           // clamp; masked later
    return in2 + ((size_t)(b * C_) * H_ + row) * W_ + x; // 16B-aligned
}

__global__ __launch_bounds__(NTHR) void corr_hx16_kernel(
    const float* __restrict__ in1,
    const float* __restrict__ in2,
    float* __restrict__ out)
{
    __shared__ __align__(16) unsigned lds[NBUF * BUF_B / 4];   // 14336 B

    const int tid = threadIdx.x;
    const int b   = blockIdx.x & 7;       // XCD swizzle: batch pinned to XCD
    const int idx = blockIdx.x >> 3;      // 0..191
    const int y   = idx >> 1;
    const int h   = idx & 1;              // x half

    // ---- staging slot (1 per thread; invalid for tid >= 218)
    int w0off = 0;
    const bool v0 = tid < NSEG;
    const float* p0 = in1;                // safe dummy (advances within in1)
    if (v0) p0 = seg_src(tid, b, y, h, in1, in2, &w0off);

    // ---- compute coords (lanes 0..179): dy-major
    const bool isComp = (tid < NCOMP);
    const int  dy = isComp ? (tid / NXG) : 0;
    const int  xg = isComp ? (tid % NXG) : 0;
    const int  x0 = 80 * h + TX * xg;
    const bool rowOk = (y + dy - 4 >= 0) && (y + dy - 4 < H_);
    const bool mzW0 = (h == 0) && (xg == 0);        // words x [-4,0)
    const bool mzW2 = (h == 1) && (xg == NXG - 1);  // words x [160,164)

    const int aof = 16 * xg;                         // in1 words [4xg, 4xg+4)
    const int wof = IN2_OFF + dy * ROW_B + 16 * xg;  // in2 words [4xg-4,4xg+8)

    float acc[ND][TX];
    #pragma unroll
    for (int dx = 0; dx < ND; ++dx)
        #pragma unroll
        for (int j = 0; j < TX; ++j) acc[dx][j] = 0.f;

    // staging register sets (letter-first suffixes: R17 pp-number paste bug)
    float4 SAp0, SAp1;
    float4 SBp0, SBp1;

    #define LOADS(S) do {                                                     \
        S##p0 = *(const float4*)(p0);  S##p1 = *(const float4*)(p0 + HW);     \
        p0 += CHSTEP;                                                         \
    } while (0);

    #define CVTW(BUFI, S) do {                                                \
        if (v0) {                                                             \
            char* base = (char*)lds + (BUFI) * BUF_B;                         \
            *(uint4*)(base + w0off) = make_uint4(                             \
                pk(S##p0.x, S##p1.x), pk(S##p0.y, S##p1.y),                   \
                pk(S##p0.z, S##p1.z), pk(S##p0.w, S##p1.w));                  \
        }                                                                     \
    } while (0);

    #define COMPUTE(BUFI)                                                     \
    if (isComp) {                                                             \
        const char* bb = (const char*)lds + (BUFI) * BUF_B;                   \
        uint4 A0 = *(const uint4*)(bb + aof);                                 \
        uint4 W0 = *(const uint4*)(bb + wof);                                 \
        uint4 W1 = *(const uint4*)(bb + wof + 16);                            \
        uint4 W2 = *(const uint4*)(bb + wof + 32);                            \
        if (mzW0) W0 = make_uint4(0u, 0u, 0u, 0u);                            \
        if (mzW2) W2 = make_uint4(0u, 0u, 0u, 0u);                            \
        unsigned a[4]  = {A0.x, A0.y, A0.z, A0.w};                            \
        unsigned w[12] = {W0.x, W0.y, W0.z, W0.w, W1.x, W1.y, W1.z, W1.w,     \
                          W2.x, W2.y, W2.z, W2.w};                            \
        _Pragma("unroll")                                                     \
        for (int dx = 0; dx < ND; ++dx) {                                     \
            _Pragma("unroll")                                                 \
            for (int j = 0; j < TX; ++j)                                      \
                acc[dx][j] = dot2acc(a[j], w[dx + j], acc[dx][j]);            \
        }                                                                     \
    }

    // body kc (buf kc&3): CVTW chunk kc+2 (regs loaded last body) into buf
    // (kc+2)&3; LOADS kc+3; COMPUTE kc (written 2 bodies + 2 barriers ago);
    // ONE __syncthreads per chunk.
    #define BODY(KM4, SWR, SLD, DOW, DOL)                                     \
        if (DOW) { CVTW(((KM4) + 2) & 3, SWR) }                               \
        if (DOL) { LOADS(SLD) }                                               \
        COMPUTE(KM4)                                                          \
        __syncthreads();

    // ---- prologue: c0->buf0, c1->buf1 (via SA), c2 -> SB regs
    LOADS(SA)          // c0
    CVTW(0, SA)
    LOADS(SA)          // c1
    CVTW(1, SA)
    LOADS(SB)          // c2
    __syncthreads();

    // ---- main loop: kc = 0..123
    #pragma unroll 1
    for (int g = 0; g < 31; ++g) {
        BODY(0, SB, SA, true, true)
        BODY(1, SA, SB, true, true)
        BODY(2, SB, SA, true, true)
        BODY(3, SA, SB, true, true)
    }
    // ---- tail: kc = 124..127
    BODY(0, SB, SA, true, true)    // writes c126, loads c127 -> SA
    BODY(1, SA, SB, true, false)   // writes c127
    BODY(2, SA, SA, false, false)
    BODY(3, SA, SA, false, false)

    #undef BODY
    #undef COMPUTE
    #undef CVTW
    #undef LOADS

    // ---- epilogue: OOB-dy rows output zeros via masked scale
    if (isComp) {
        const float m = rowOk ? (1.0f / (float)C_) : 0.f;
        float* outp = out + ((size_t)(b * NDISP + dy * ND) * H_ + y) * W_ + x0;
        #pragma unroll
        for (int dx = 0; dx < ND; ++dx) {
            float4 o = make_float4(acc[dx][0] * m, acc[dx][1] * m,
                                   acc[dx][2] * m, acc[dx][3] * m);
            *(float4*)(outp + dx * HW) = o;
        }
    }
}

extern "C" void kernel_launch(void* const* d_in, const int* in_sizes, int n_in,
                              void* d_out, int out_size, void* d_ws, size_t ws_size,
                              hipStream_t stream) {
    const float* in1 = (const float*)d_in[0];
    const float* in2 = (const float*)d_in[1];
    float* out = (float*)d_out;

    const int grid = B_ * H_ * 2;   // 1536 blocks (b, y, half) = 6 per CU
    corr_hx16_kernel<<<grid, NTHR, 0, stream>>>(in1, in2, out);
}